// Round 16
// baseline (413.296 us; speedup 1.0000x reference)
//
#include <hip/hip_runtime.h>
#include <stdint.h>

#define CIN  128
#define COUT 256
#define HH   256
#define WW   256
#define BSZ  32
#define HB   8
#define WB   8
#define NBLK 256
#define P2   34          // padded block dim (32 + halo)
#define PIX2 1156        // 34*34

typedef __attribute__((ext_vector_type(8))) short bfx8;
typedef __attribute__((ext_vector_type(4))) float f32x4;

#define MFMA(a,b,c) __builtin_amdgcn_mfma_f32_16x16x32_bf16((a),(b),(c),0,0,0)

typedef const __attribute__((address_space(1))) unsigned int gu32;
typedef __attribute__((address_space(3))) unsigned int lu32;
#define GLOAD16(g, p) __builtin_amdgcn_global_load_lds((gu32*)(g), (lu32*)(p), 16, 0, 0)

static __device__ __forceinline__ float bf2f(unsigned short u){
  union { unsigned int i; float f; } v; v.i = ((unsigned int)u)<<16; return v.f;
}
static __device__ __forceinline__ unsigned short f2bf(float f){
  union { float f; unsigned int i; } v; v.f = f;
  unsigned int r = v.i + 0x7fffu + ((v.i>>16)&1u);
  return (unsigned short)(r>>16);
}

// ---------------- prep: weights -> bf16; absorbs part-zeroing + inactive-list build.
__global__ void k_prep(const float* __restrict__ w1, const float* __restrict__ wd,
                       const float* __restrict__ w2,
                       unsigned short* __restrict__ w1b, unsigned short* __restrict__ wdb,
                       unsigned short* __restrict__ w2t,
                       const int* __restrict__ bidx, int nact, int* __restrict__ inact,
                       float* __restrict__ part1, float* __restrict__ part2){
  __shared__ int fl[NBLK];
  int bid = blockIdx.x, t = threadIdx.x;
  if (bid < 2304){
    int i = bid*256 + t;
    if (i < COUT*CIN){ w1b[i] = f2bf(w1[i]); wdb[i] = f2bf(wd[i]); }
    if (i < COUT*COUT*9){
      int co = i/2304, r = i - co*2304;
      int ci = r/9,   tp = r - ci*9;
      w2t[((size_t)tp*COUT + co)*COUT + ci] = f2bf(w2[i]);
    }
  } else if (bid < 2308){
    float4 z = make_float4(0.f,0.f,0.f,0.f);
    float* p = part1 + ((size_t)(bid-2304)*256 + t)*8;
    *(float4*)p = z; *(float4*)(p+4) = z;
  } else if (bid < 2312){
    float4 z = make_float4(0.f,0.f,0.f,0.f);
    float* p = part2 + ((size_t)(bid-2308)*256 + t)*8;
    *(float4*)p = z; *(float4*)(p+4) = z;
  } else {
    fl[t] = 0;
    __syncthreads();
    if (t < nact){
      int f = bidx[t*3]*(HB*WB) + bidx[t*3+1]*WB + bidx[t*3+2];
      fl[f] = 1;
    }
    __syncthreads();
    if (t == 0){
      int c = 0;
      for (int f = 0; f < NBLK; ++f) if (!fl[f]) inact[c++] = f;
    }
  }
}

// ---------------- 1x1 GEMM, merged active+base paths in ONE launch.
// z < nact  : conv1 on active block  -> h1p bf16 raw + halo zeros + BN1 partials
// z >= nact : base 1x1 on inactive   -> out f32 + bd
// Natural grid dim3(8,2,NBLK) — R12 proved XCD swizzles regress.
__global__ __launch_bounds__(256) void k_gemm1(
    const float* __restrict__ x, const unsigned short* __restrict__ w1b,
    const unsigned short* __restrict__ wdb,
    const int* __restrict__ bidx, const int* __restrict__ inact,
    const float* __restrict__ bd, unsigned short* __restrict__ h1p,
    float* __restrict__ out, float* __restrict__ part, int nact){
  __shared__ unsigned short lds[2*5120];   // 2 buf x 128 px x pitch 40
  int rg = blockIdx.x, cot = blockIdx.y, zz = blockIdx.z;
  bool active = (zz < nact);
  int z = active ? zz : (zz - nact);
  int bi, by, bx;
  if (active){ bi = bidx[z*3]; by = bidx[z*3+1]; bx = bidx[z*3+2]; }
  else { int fl = inact[z]; bi = fl>>6; by = (fl>>3)&7; bx = fl&7; }
  const unsigned short* wgt = active ? w1b : wdb;
  int t = threadIdx.x, l = t&63, wid = t>>6;
  int wc = wid>>1, wp = wid&1;
  int y0 = rg*4;
  int co_w = cot*128 + wc*64;

  // full weight slice in registers (16 frags = 64 VGPR)
  const unsigned short* wb = wgt + (size_t)(co_w + (l&15))*CIN + ((l>>4)*8);
  bfx8 wfrag[4][4];
  #pragma unroll
  for (int kc = 0; kc < 4; ++kc)
    #pragma unroll
    for (int m = 0; m < 4; ++m)
      wfrag[kc][m] = *(const bfx8*)(wb + kc*32 + (size_t)m*16*CIN);

  // x staging: units u = t, 256+t : ci_pair = u>>5 (x2 ci), pxg = u&31 (x4 px)
  const float* xb = x + (size_t)bi*CIN*HH*WW + (size_t)(by*BSZ + y0)*WW + bx*BSZ;
  float4 ra[2], rb_[2];
  auto ldreg = [&](int kc){
    #pragma unroll
    for (int j = 0; j < 2; ++j){
      int u = j*256 + t;
      int ci0 = (u>>5)*2 + kc*32;
      int p = (u&31)*4;
      const float* s = xb + (size_t)ci0*(HH*WW) + (p>>5)*WW + (p&31);
      ra[j]  = *(const float4*)s;
      rb_[j] = *(const float4*)(s + HH*WW);
    }
  };
  auto wrlds = [&](int buf){
    #pragma unroll
    for (int j = 0; j < 2; ++j){
      int u = j*256 + t;
      int ci0 = (u>>5)*2;
      int p = (u&31)*4;
      unsigned short* d = &lds[buf*5120 + ci0];
      *(ushort2*)&d[(p+0)*40] = make_ushort2(f2bf(ra[j].x), f2bf(rb_[j].x));
      *(ushort2*)&d[(p+1)*40] = make_ushort2(f2bf(ra[j].y), f2bf(rb_[j].y));
      *(ushort2*)&d[(p+2)*40] = make_ushort2(f2bf(ra[j].z), f2bf(rb_[j].z));
      *(ushort2*)&d[(p+3)*40] = make_ushort2(f2bf(ra[j].w), f2bf(rb_[j].w));
    }
  };

  f32x4 acc[4][4] = {};
  ldreg(0);
  for (int kc = 0; kc < 4; ++kc){
    wrlds(kc&1);
    if (kc < 3) ldreg(kc+1);   // in flight across barrier+compute
    __syncthreads();
    const unsigned short* lb = &lds[(kc&1)*5120];
    #pragma unroll
    for (int f = 0; f < 4; ++f){
      bfx8 b = *(const bfx8*)&lb[(wp*64 + f*16 + (l&15))*40 + (l>>4)*8];
      acc[0][f] = MFMA(wfrag[kc][0], b, acc[0][f]);
      acc[1][f] = MFMA(wfrag[kc][1], b, acc[1][f]);
      acc[2][f] = MFMA(wfrag[kc][2], b, acc[2][f]);
      acc[3][f] = MFMA(wfrag[kc][3], b, acc[3][f]);
    }
  }

  #pragma unroll
  for (int m = 0; m < 4; ++m){
    int co = co_w + m*16 + ((l>>4)<<2);
    #pragma unroll
    for (int f = 0; f < 4; ++f){
      int px = wp*64 + f*16 + (l&15);
      int ly = px>>5, lx = px&31;
      if (active){
        *(ushort4*)&h1p[((size_t)z*PIX2 + (size_t)(y0+ly+1)*P2 + (lx+1))*COUT + co] =
          make_ushort4(f2bf(acc[m][f][0]), f2bf(acc[m][f][1]),
                       f2bf(acc[m][f][2]), f2bf(acc[m][f][3]));
      } else {
        int gy = by*BSZ + y0 + ly, gx = bx*BSZ + lx;
        #pragma unroll
        for (int j = 0; j < 4; ++j)
          out[(((size_t)bi*COUT + co + j)*HH + gy)*WW + gx] = acc[m][f][j] + bd[co+j];
      }
    }
  }

  if (active){
    // halo zeroing: 132 halo pixels per block, split across the block's 16 WGs.
    int hwi = rg*2 + cot;          // 0..15
    #pragma unroll
    for (int pass = 0; pass < 2; ++pass){
      int j = pass*8 + (t>>5);
      if (j < 9){
        int hp = hwi*9 + j;
        if (hp < 132){
          int r, c;
          if (hp < 34){ r = 0; c = hp; }
          else if (hp < 68){ r = 33; c = hp - 34; }
          else if (hp < 100){ r = hp - 67; c = 0; }
          else { r = hp - 99; c = 33; }
          bfx8 z8 = {};
          *(bfx8*)&h1p[((size_t)z*PIX2 + (size_t)r*P2 + c)*COUT + (t&31)*8] = z8;
        }
      }
    }

    // BN1 stat partials
    float s_[4][4], q_[4][4];
    #pragma unroll
    for (int m = 0; m < 4; ++m)
      #pragma unroll
      for (int j = 0; j < 4; ++j){
        float s = 0.f, q = 0.f;
        #pragma unroll
        for (int f = 0; f < 4; ++f){ float v = acc[m][f][j]; s += v; q += v*v; }
        s_[m][j] = s; q_[m][j] = q;
      }
    #pragma unroll
    for (int off = 1; off < 16; off <<= 1)
      #pragma unroll
      for (int m = 0; m < 4; ++m)
        #pragma unroll
        for (int j = 0; j < 4; ++j){
          s_[m][j] += __shfl_xor(s_[m][j], off);
          q_[m][j] += __shfl_xor(q_[m][j], off);
        }
    if ((l&15) == 0){
      int grp = z & 15;
      #pragma unroll
      for (int m = 0; m < 4; ++m)
        #pragma unroll
        for (int j = 0; j < 4; ++j){
          int co = co_w + m*16 + ((l>>4)<<2) + j;
          atomicAdd(&part[((size_t)grp*COUT + co)*2],   s_[m][j]);
          atomicAdd(&part[((size_t)grp*COUT + co)*2+1], q_[m][j]);
        }
    }
  }
}

// ---------------- BN1: inline fin (per-WG channel reduce, L2-resident partials)
// + apply + ReLU, INTERIOR ONLY (halo zeroed by gemm1 active path).
__global__ void k_bn1(unsigned short* __restrict__ h1p, const float* __restrict__ part,
                      const float* __restrict__ g, const float* __restrict__ be, float inv){
  __shared__ float sst[512];
  int t = threadIdx.x;
  {
    float s = 0.f, q = 0.f;
    #pragma unroll
    for (int gi = 0; gi < 16; ++gi){
      const float* p = part + ((size_t)gi*COUT + t)*2;
      s += p[0]; q += p[1];
    }
    float mu = s*inv, var = q*inv - mu*mu;
    float sc = g[t]*rsqrtf(var + 1e-5f);
    sst[t] = sc; sst[256+t] = be[t] - mu*sc;
  }
  __syncthreads();
  int ci0 = (t&31)*8;
  float sc[8], tc[8];
  #pragma unroll
  for (int j = 0; j < 8; ++j){ sc[j] = sst[ci0+j]; tc[j] = sst[256+ci0+j]; }
  #pragma unroll
  for (int it = 0; it < 4; ++it){
    int gp = blockIdx.x*32 + it*8 + (t>>5);   // global interior px id
    int n = gp >> 10, p = gp & 1023;
    int row = (p>>5) + 1, col = (p&31) + 1;
    unsigned short* addr = h1p + ((size_t)n*PIX2 + (size_t)row*P2 + col)*COUT + ci0;
    bfx8 v = *(bfx8*)addr;
    unsigned short o[8];
    #pragma unroll
    for (int j = 0; j < 8; ++j){
      float f = bf2f(((unsigned short*)&v)[j]);
      o[j] = f2bf(fmaxf(f*sc[j] + tc[j], 0.f));
    }
    *(bfx8*)addr = *(bfx8*)o;
  }
}

// ---------------- conv2 as GEMM: C[256co][128px] += W[256co][K] * Im2col[K][128px]
// R13-exact (validated LDS-BW roofline config): grid dim3(8, nact) NATURAL order,
// 48KB single-buffer LDS, 8 waves (4M x 2N), wave 64x64 acc[4][4], 2 WG/CU anti-phase.
__global__ __launch_bounds__(512, 4) void k_conv2(
    const unsigned short* __restrict__ h1p, const unsigned short* __restrict__ w2t,
    const int* __restrict__ bidx, float* __restrict__ out, float* __restrict__ part){
  __shared__ unsigned short lds[24576];   // A[256][64] 32KB | B[128][64] 16KB
  int bxid = blockIdx.x, n = blockIdx.y;
  int h = bxid & 1, q = bxid >> 1;        // px-half, quarter
  int bi = bidx[n*3], by = bidx[n*3+1], bx = bidx[n*3+2];
  int t = threadIdx.x, l = t&63, wid = t>>6;
  int wm = wid>>1, wn = wid&1;            // 4M x 2N
  int y0 = q*8;

  // staging invariants: task i -> row=i>>3, slot=i&7
  // LDS[row][slot] <- global[row][slot ^ (row&7)]  (linear dest, pre-swizzled source)
  int offA[4], offB[2];
  #pragma unroll
  for (int j = 0; j < 4; ++j){
    int i = j*512 + t;
    int row = i>>3, sl_ = i&7;
    offA[j] = row*COUT + (sl_ ^ (row&7))*8;
  }
  #pragma unroll
  for (int j = 0; j < 2; ++j){
    int i = j*512 + t;
    int row = i>>3, sl_ = i&7;
    offB[j] = ((row>>5)*P2 + (row&31))*COUT + (sl_ ^ (row&7))*8;
  }
  const unsigned short* h1q = h1p + ((size_t)n*PIX2 + (size_t)(y0 + h*4)*P2)*COUT;

  int lr = l&15, lh = l>>4;
  f32x4 acc[4][4] = {};

  for (int s = 0; s < 36; ++s){
    int tp = s>>2, cc = s&3;
    int dy = tp/3, dx = tp - dy*3;
    const unsigned short* wsrc = w2t + (size_t)tp*COUT*COUT + cc*64;
    const unsigned short* psrc = h1q + (size_t)(dy*P2 + dx)*COUT + cc*64;
    __syncthreads();            // previous step's compute fully done (single buffer)
    #pragma unroll
    for (int j = 0; j < 4; ++j)
      GLOAD16(wsrc + offA[j], &lds[(j*512 + t)*8]);
    #pragma unroll
    for (int j = 0; j < 2; ++j)
      GLOAD16(psrc + offB[j], &lds[16384 + (j*512 + t)*8]);
    __syncthreads();            // vmcnt(0) drain: LDS tiles ready
    #pragma unroll
    for (int kk = 0; kk < 2; ++kk){
      bfx8 af[4], bfr[4];
      #pragma unroll
      for (int m = 0; m < 4; ++m)
        af[m] = *(const bfx8*)&lds[(wm*64 + m*16 + lr)*64 + ((kk*4 + lh) ^ (lr&7))*8];
      #pragma unroll
      for (int nn = 0; nn < 4; ++nn)
        bfr[nn] = *(const bfx8*)&lds[16384 + (wn*64 + nn*16 + lr)*64 + ((kk*4 + lh) ^ (lr&7))*8];
      #pragma unroll
      for (int m = 0; m < 4; ++m)
        #pragma unroll
        for (int nn = 0; nn < 4; ++nn)
          acc[m][nn] = MFMA(af[m], bfr[nn], acc[m][nn]);
    }
  }

  // epilogue: raw h2 -> out active positions
  #pragma unroll
  for (int m = 0; m < 4; ++m){
    int co = wm*64 + m*16 + lh*4;
    #pragma unroll
    for (int nn = 0; nn < 4; ++nn){
      int px = h*128 + wn*64 + nn*16 + lr;
      int gy = by*BSZ + y0 + (px>>5), gx = bx*BSZ + (px&31);
      #pragma unroll
      for (int j = 0; j < 4; ++j)
        out[(((size_t)bi*COUT + co + j)*HH + gy)*WW + gx] = acc[m][nn][j];
    }
  }

  // BN2 stat partials
  #pragma unroll
  for (int m = 0; m < 4; ++m){
    #pragma unroll
    for (int j = 0; j < 4; ++j){
      float s = 0.f, qq = 0.f;
      #pragma unroll
      for (int nn = 0; nn < 4; ++nn){ float v = acc[m][nn][j]; s += v; qq += v*v; }
      #pragma unroll
      for (int off = 1; off < 16; off <<= 1){
        s  += __shfl_xor(s,  off);
        qq += __shfl_xor(qq, off);
      }
      if (lr == 0){
        int co = wm*64 + m*16 + lh*4 + j;
        atomicAdd(&part[((size_t)(n&15)*COUT + co)*2],   s);
        atomicAdd(&part[((size_t)(n&15)*COUT + co)*2+1], qq);
      }
    }
  }
}

// ---------------- BN2: inline fin + apply + ReLU in place on d_out active blocks ----------------
__global__ void k_bn2(float* __restrict__ out, const int* __restrict__ bidx,
                      const float* __restrict__ part, const float* __restrict__ g,
                      const float* __restrict__ be, float inv){
  __shared__ float sst[512];
  int cq = blockIdx.x, n = blockIdx.y, t = threadIdx.x;
  {
    float s = 0.f, q = 0.f;
    #pragma unroll
    for (int gi = 0; gi < 16; ++gi){
      const float* p = part + ((size_t)gi*COUT + t)*2;
      s += p[0]; q += p[1];
    }
    float mu = s*inv, var = q*inv - mu*mu;
    float sc = g[t]*rsqrtf(var + 1e-5f);
    sst[t] = sc; sst[256+t] = be[t] - mu*sc;
  }
  __syncthreads();
  int bi = bidx[n*3], by = bidx[n*3+1], bx = bidx[n*3+2];
  int px0 = t*4; int ly = px0>>5, lx = px0&31;
  float* base = out + (size_t)bi*COUT*HH*WW + (size_t)(by*BSZ+ly)*WW + bx*BSZ + lx;
  for (int c = 0; c < 64; ++c){
    int co = cq*64 + c;
    float sc = sst[co], tc = sst[256+co];
    float4* p = (float4*)(base + (size_t)co*HH*WW);
    float4 v = *p;
    v.x = fmaxf(v.x*sc+tc, 0.f); v.y = fmaxf(v.y*sc+tc, 0.f);
    v.z = fmaxf(v.z*sc+tc, 0.f); v.w = fmaxf(v.w*sc+tc, 0.f);
    *p = v;
  }
}

extern "C" void kernel_launch(void* const* d_in, const int* in_sizes, int n_in,
                              void* d_out, int out_size, void* d_ws, size_t ws_size,
                              hipStream_t stream){
  const float* x   = (const float*)d_in[0];
  const float* w1  = (const float*)d_in[1];
  const float* g1  = (const float*)d_in[3];
  const float* be1 = (const float*)d_in[4];
  const float* w2  = (const float*)d_in[5];
  const float* g2  = (const float*)d_in[7];
  const float* be2 = (const float*)d_in[8];
  const float* wd  = (const float*)d_in[9];
  const float* bd  = (const float*)d_in[10];
  const int* bidx  = (const int*)d_in[11];
  float* out = (float*)d_out;
  const int nact = in_sizes[11]/3;     // 128

  char* wsp = (char*)d_ws;
  size_t off = 0;
  auto carve = [&](size_t bytes)->char*{
    char* p = wsp + off; off += (bytes + 255) & ~(size_t)255; return p;
  };
  unsigned short* h1p = (unsigned short*)carve((size_t)nact*PIX2*COUT*2 + 4096);
  unsigned short* w1b = (unsigned short*)carve((size_t)COUT*CIN*2);
  unsigned short* wdb = (unsigned short*)carve((size_t)COUT*CIN*2);
  unsigned short* w2t = (unsigned short*)carve((size_t)9*COUT*COUT*2);
  float* part1 = (float*)carve((size_t)16*COUT*2*4);
  float* part2 = (float*)carve((size_t)16*COUT*2*4);
  int* inact   = (int*)carve(NBLK*4);

  const float inv = 1.0f/((float)nact*1024.0f);
  k_prep<<<2313, 256, 0, stream>>>(w1, wd, w2, w1b, wdb, w2t,
                                   bidx, nact, inact, part1, part2);
  k_gemm1<<<dim3(8, 2, NBLK), 256, 0, stream>>>(x, w1b, wdb, bidx, inact, bd,
                                                h1p, out, part1, nact);
  k_bn1<<<dim3(nact*32), 256, 0, stream>>>(h1p, part1, g1, be1, inv);
  k_conv2<<<dim3(8, nact), 512, 0, stream>>>(h1p, w2t, bidx, out, part2);
  k_bn2<<<dim3(4, nact), 256, 0, stream>>>(out, bidx, part2, g2, be2, inv);
}

// Round 17
// 392.324 us; speedup vs baseline: 1.0535x; 1.0535x over previous
//
#include <hip/hip_runtime.h>
#include <stdint.h>

#define CIN  128
#define COUT 256
#define HH   256
#define WW   256
#define BSZ  32
#define HB   8
#define WB   8
#define NBLK 256
#define P2   34          // padded block dim (32 + halo)
#define PIX2 1156        // 34*34

typedef __attribute__((ext_vector_type(8))) short bfx8;
typedef __attribute__((ext_vector_type(4))) float f32x4;

#define MFMA(a,b,c) __builtin_amdgcn_mfma_f32_16x16x32_bf16((a),(b),(c),0,0,0)

typedef const __attribute__((address_space(1))) unsigned int gu32;
typedef __attribute__((address_space(3))) unsigned int lu32;
#define GLOAD16(g, p) __builtin_amdgcn_global_load_lds((gu32*)(g), (lu32*)(p), 16, 0, 0)

static __device__ __forceinline__ float bf2f(unsigned short u){
  union { unsigned int i; float f; } v; v.i = ((unsigned int)u)<<16; return v.f;
}
static __device__ __forceinline__ unsigned short f2bf(float f){
  union { float f; unsigned int i; } v; v.f = f;
  unsigned int r = v.i + 0x7fffu + ((v.i>>16)&1u);
  return (unsigned short)(r>>16);
}

// ---------------- prep: weights -> bf16; absorbs part-zeroing + inactive-list build.
__global__ void k_prep(const float* __restrict__ w1, const float* __restrict__ wd,
                       const float* __restrict__ w2,
                       unsigned short* __restrict__ w1b, unsigned short* __restrict__ wdb,
                       unsigned short* __restrict__ w2t,
                       const int* __restrict__ bidx, int nact, int* __restrict__ inact,
                       float* __restrict__ part1, float* __restrict__ part2){
  __shared__ int fl[NBLK];
  int bid = blockIdx.x, t = threadIdx.x;
  if (bid < 2304){
    int i = bid*256 + t;
    if (i < COUT*CIN){ w1b[i] = f2bf(w1[i]); wdb[i] = f2bf(wd[i]); }
    if (i < COUT*COUT*9){
      int co = i/2304, r = i - co*2304;
      int ci = r/9,   tp = r - ci*9;
      w2t[((size_t)tp*COUT + co)*COUT + ci] = f2bf(w2[i]);
    }
  } else if (bid < 2308){
    float4 z = make_float4(0.f,0.f,0.f,0.f);
    float* p = part1 + ((size_t)(bid-2304)*256 + t)*8;
    *(float4*)p = z; *(float4*)(p+4) = z;
  } else if (bid < 2312){
    float4 z = make_float4(0.f,0.f,0.f,0.f);
    float* p = part2 + ((size_t)(bid-2308)*256 + t)*8;
    *(float4*)p = z; *(float4*)(p+4) = z;
  } else {
    fl[t] = 0;
    __syncthreads();
    if (t < nact){
      int f = bidx[t*3]*(HB*WB) + bidx[t*3+1]*WB + bidx[t*3+2];
      fl[f] = 1;
    }
    __syncthreads();
    if (t == 0){
      int c = 0;
      for (int f = 0; f < NBLK; ++f) if (!fl[f]) inact[c++] = f;
    }
  }
}

// ---------------- 1x1 GEMM, merged active+base paths in ONE launch.
// z < nact  : conv1 on active block  -> h1p bf16 raw + halo zeros + BN1 partials
// z >= nact : base 1x1 on inactive   -> out f32 + bd
__global__ __launch_bounds__(256) void k_gemm1(
    const float* __restrict__ x, const unsigned short* __restrict__ w1b,
    const unsigned short* __restrict__ wdb,
    const int* __restrict__ bidx, const int* __restrict__ inact,
    const float* __restrict__ bd, unsigned short* __restrict__ h1p,
    float* __restrict__ out, float* __restrict__ part, int nact){
  __shared__ unsigned short lds[2*5120];   // 2 buf x 128 px x pitch 40
  int rg = blockIdx.x, cot = blockIdx.y, zz = blockIdx.z;
  bool active = (zz < nact);
  int z = active ? zz : (zz - nact);
  int bi, by, bx;
  if (active){ bi = bidx[z*3]; by = bidx[z*3+1]; bx = bidx[z*3+2]; }
  else { int fl = inact[z]; bi = fl>>6; by = (fl>>3)&7; bx = fl&7; }
  const unsigned short* wgt = active ? w1b : wdb;
  int t = threadIdx.x, l = t&63, wid = t>>6;
  int wc = wid>>1, wp = wid&1;
  int y0 = rg*4;
  int co_w = cot*128 + wc*64;

  // full weight slice in registers (16 frags = 64 VGPR)
  const unsigned short* wb = wgt + (size_t)(co_w + (l&15))*CIN + ((l>>4)*8);
  bfx8 wfrag[4][4];
  #pragma unroll
  for (int kc = 0; kc < 4; ++kc)
    #pragma unroll
    for (int m = 0; m < 4; ++m)
      wfrag[kc][m] = *(const bfx8*)(wb + kc*32 + (size_t)m*16*CIN);

  // x staging: units u = t, 256+t : ci_pair = u>>5 (x2 ci), pxg = u&31 (x4 px)
  const float* xb = x + (size_t)bi*CIN*HH*WW + (size_t)(by*BSZ + y0)*WW + bx*BSZ;
  float4 ra[2], rb_[2];
  auto ldreg = [&](int kc){
    #pragma unroll
    for (int j = 0; j < 2; ++j){
      int u = j*256 + t;
      int ci0 = (u>>5)*2 + kc*32;
      int p = (u&31)*4;
      const float* s = xb + (size_t)ci0*(HH*WW) + (p>>5)*WW + (p&31);
      ra[j]  = *(const float4*)s;
      rb_[j] = *(const float4*)(s + HH*WW);
    }
  };
  auto wrlds = [&](int buf){
    #pragma unroll
    for (int j = 0; j < 2; ++j){
      int u = j*256 + t;
      int ci0 = (u>>5)*2;
      int p = (u&31)*4;
      unsigned short* d = &lds[buf*5120 + ci0];
      *(ushort2*)&d[(p+0)*40] = make_ushort2(f2bf(ra[j].x), f2bf(rb_[j].x));
      *(ushort2*)&d[(p+1)*40] = make_ushort2(f2bf(ra[j].y), f2bf(rb_[j].y));
      *(ushort2*)&d[(p+2)*40] = make_ushort2(f2bf(ra[j].z), f2bf(rb_[j].z));
      *(ushort2*)&d[(p+3)*40] = make_ushort2(f2bf(ra[j].w), f2bf(rb_[j].w));
    }
  };

  f32x4 acc[4][4] = {};
  ldreg(0);
  for (int kc = 0; kc < 4; ++kc){
    wrlds(kc&1);
    if (kc < 3) ldreg(kc+1);   // in flight across barrier+compute
    __syncthreads();
    const unsigned short* lb = &lds[(kc&1)*5120];
    #pragma unroll
    for (int f = 0; f < 4; ++f){
      bfx8 b = *(const bfx8*)&lb[(wp*64 + f*16 + (l&15))*40 + (l>>4)*8];
      acc[0][f] = MFMA(wfrag[kc][0], b, acc[0][f]);
      acc[1][f] = MFMA(wfrag[kc][1], b, acc[1][f]);
      acc[2][f] = MFMA(wfrag[kc][2], b, acc[2][f]);
      acc[3][f] = MFMA(wfrag[kc][3], b, acc[3][f]);
    }
  }

  #pragma unroll
  for (int m = 0; m < 4; ++m){
    int co = co_w + m*16 + ((l>>4)<<2);
    #pragma unroll
    for (int f = 0; f < 4; ++f){
      int px = wp*64 + f*16 + (l&15);
      int ly = px>>5, lx = px&31;
      if (active){
        *(ushort4*)&h1p[((size_t)z*PIX2 + (size_t)(y0+ly+1)*P2 + (lx+1))*COUT + co] =
          make_ushort4(f2bf(acc[m][f][0]), f2bf(acc[m][f][1]),
                       f2bf(acc[m][f][2]), f2bf(acc[m][f][3]));
      } else {
        int gy = by*BSZ + y0 + ly, gx = bx*BSZ + lx;
        #pragma unroll
        for (int j = 0; j < 4; ++j)
          out[(((size_t)bi*COUT + co + j)*HH + gy)*WW + gx] = acc[m][f][j] + bd[co+j];
      }
    }
  }

  if (active){
    // halo zeroing: 132 halo pixels per block, split across the block's 16 WGs.
    int hwi = rg*2 + cot;          // 0..15
    #pragma unroll
    for (int pass = 0; pass < 2; ++pass){
      int j = pass*8 + (t>>5);
      if (j < 9){
        int hp = hwi*9 + j;
        if (hp < 132){
          int r, c;
          if (hp < 34){ r = 0; c = hp; }
          else if (hp < 68){ r = 33; c = hp - 34; }
          else if (hp < 100){ r = hp - 67; c = 0; }
          else { r = hp - 99; c = 33; }
          bfx8 z8 = {};
          *(bfx8*)&h1p[((size_t)z*PIX2 + (size_t)r*P2 + c)*COUT + (t&31)*8] = z8;
        }
      }
    }

    // BN1 stat partials
    float s_[4][4], q_[4][4];
    #pragma unroll
    for (int m = 0; m < 4; ++m)
      #pragma unroll
      for (int j = 0; j < 4; ++j){
        float s = 0.f, q = 0.f;
        #pragma unroll
        for (int f = 0; f < 4; ++f){ float v = acc[m][f][j]; s += v; q += v*v; }
        s_[m][j] = s; q_[m][j] = q;
      }
    #pragma unroll
    for (int off = 1; off < 16; off <<= 1)
      #pragma unroll
      for (int m = 0; m < 4; ++m)
        #pragma unroll
        for (int j = 0; j < 4; ++j){
          s_[m][j] += __shfl_xor(s_[m][j], off);
          q_[m][j] += __shfl_xor(q_[m][j], off);
        }
    if ((l&15) == 0){
      int grp = z & 15;
      #pragma unroll
      for (int m = 0; m < 4; ++m)
        #pragma unroll
        for (int j = 0; j < 4; ++j){
          int co = co_w + m*16 + ((l>>4)<<2) + j;
          atomicAdd(&part[((size_t)grp*COUT + co)*2],   s_[m][j]);
          atomicAdd(&part[((size_t)grp*COUT + co)*2+1], q_[m][j]);
        }
    }
  }
}

// ---------------- BN1: inline fin + apply + ReLU, INTERIOR ONLY ----------------
__global__ void k_bn1(unsigned short* __restrict__ h1p, const float* __restrict__ part,
                      const float* __restrict__ g, const float* __restrict__ be, float inv){
  __shared__ float sst[512];
  int t = threadIdx.x;
  {
    float s = 0.f, q = 0.f;
    #pragma unroll
    for (int gi = 0; gi < 16; ++gi){
      const float* p = part + ((size_t)gi*COUT + t)*2;
      s += p[0]; q += p[1];
    }
    float mu = s*inv, var = q*inv - mu*mu;
    float sc = g[t]*rsqrtf(var + 1e-5f);
    sst[t] = sc; sst[256+t] = be[t] - mu*sc;
  }
  __syncthreads();
  int ci0 = (t&31)*8;
  float sc[8], tc[8];
  #pragma unroll
  for (int j = 0; j < 8; ++j){ sc[j] = sst[ci0+j]; tc[j] = sst[256+ci0+j]; }
  #pragma unroll
  for (int it = 0; it < 4; ++it){
    int gp = blockIdx.x*32 + it*8 + (t>>5);   // global interior px id
    int n = gp >> 10, p = gp & 1023;
    int row = (p>>5) + 1, col = (p&31) + 1;
    unsigned short* addr = h1p + ((size_t)n*PIX2 + (size_t)row*P2 + col)*COUT + ci0;
    bfx8 v = *(bfx8*)addr;
    unsigned short o[8];
    #pragma unroll
    for (int j = 0; j < 8; ++j){
      float f = bf2f(((unsigned short*)&v)[j]);
      o[j] = f2bf(fmaxf(f*sc[j] + tc[j], 0.f));
    }
    *(bfx8*)addr = *(bfx8*)o;
  }
}

// ---------------- conv2 as GEMM (R13-exact core). h2 now stored as bf16 to
// workspace h2b[n][co][px] (67MB) instead of f32 to out (134MB): halves the
// h2 write and bn2 read traffic. BN2 stats still from exact f32 acc.
__global__ __launch_bounds__(512, 4) void k_conv2(
    const unsigned short* __restrict__ h1p, const unsigned short* __restrict__ w2t,
    const int* __restrict__ bidx, unsigned short* __restrict__ h2b,
    float* __restrict__ part){
  __shared__ unsigned short lds[24576];   // A[256][64] 32KB | B[128][64] 16KB
  int bxid = blockIdx.x, n = blockIdx.y;
  int h = bxid & 1, q = bxid >> 1;        // px-half, quarter
  int t = threadIdx.x, l = t&63, wid = t>>6;
  int wm = wid>>1, wn = wid&1;            // 4M x 2N
  int y0 = q*8;

  // staging invariants: task i -> row=i>>3, slot=i&7
  // LDS[row][slot] <- global[row][slot ^ (row&7)]  (linear dest, pre-swizzled source)
  int offA[4], offB[2];
  #pragma unroll
  for (int j = 0; j < 4; ++j){
    int i = j*512 + t;
    int row = i>>3, sl_ = i&7;
    offA[j] = row*COUT + (sl_ ^ (row&7))*8;
  }
  #pragma unroll
  for (int j = 0; j < 2; ++j){
    int i = j*512 + t;
    int row = i>>3, sl_ = i&7;
    offB[j] = ((row>>5)*P2 + (row&31))*COUT + (sl_ ^ (row&7))*8;
  }
  const unsigned short* h1q = h1p + ((size_t)n*PIX2 + (size_t)(y0 + h*4)*P2)*COUT;

  int lr = l&15, lh = l>>4;
  f32x4 acc[4][4] = {};

  for (int s = 0; s < 36; ++s){
    int tp = s>>2, cc = s&3;
    int dy = tp/3, dx = tp - dy*3;
    const unsigned short* wsrc = w2t + (size_t)tp*COUT*COUT + cc*64;
    const unsigned short* psrc = h1q + (size_t)(dy*P2 + dx)*COUT + cc*64;
    __syncthreads();            // previous step's compute fully done (single buffer)
    #pragma unroll
    for (int j = 0; j < 4; ++j)
      GLOAD16(wsrc + offA[j], &lds[(j*512 + t)*8]);
    #pragma unroll
    for (int j = 0; j < 2; ++j)
      GLOAD16(psrc + offB[j], &lds[16384 + (j*512 + t)*8]);
    __syncthreads();            // vmcnt(0) drain: LDS tiles ready
    #pragma unroll
    for (int kk = 0; kk < 2; ++kk){
      bfx8 af[4], bfr[4];
      #pragma unroll
      for (int m = 0; m < 4; ++m)
        af[m] = *(const bfx8*)&lds[(wm*64 + m*16 + lr)*64 + ((kk*4 + lh) ^ (lr&7))*8];
      #pragma unroll
      for (int nn = 0; nn < 4; ++nn)
        bfr[nn] = *(const bfx8*)&lds[16384 + (wn*64 + nn*16 + lr)*64 + ((kk*4 + lh) ^ (lr&7))*8];
      #pragma unroll
      for (int m = 0; m < 4; ++m)
        #pragma unroll
        for (int nn = 0; nn < 4; ++nn)
          acc[m][nn] = MFMA(af[m], bfr[nn], acc[m][nn]);
    }
  }

  // epilogue: raw h2 -> h2b bf16 [n][co][px0..1023]
  unsigned short* h2n = h2b + ((size_t)n << 18);   // n*256*1024
  #pragma unroll
  for (int m = 0; m < 4; ++m){
    int co = wm*64 + m*16 + lh*4;
    #pragma unroll
    for (int nn = 0; nn < 4; ++nn){
      int gpx = (q<<8) + (h<<7) + wn*64 + nn*16 + lr;
      #pragma unroll
      for (int j = 0; j < 4; ++j)
        h2n[(((size_t)(co + j))<<10) + gpx] = f2bf(acc[m][nn][j]);
    }
  }

  // BN2 stat partials
  #pragma unroll
  for (int m = 0; m < 4; ++m){
    #pragma unroll
    for (int j = 0; j < 4; ++j){
      float s = 0.f, qq = 0.f;
      #pragma unroll
      for (int nn = 0; nn < 4; ++nn){ float v = acc[m][nn][j]; s += v; qq += v*v; }
      #pragma unroll
      for (int off = 1; off < 16; off <<= 1){
        s  += __shfl_xor(s,  off);
        qq += __shfl_xor(qq, off);
      }
      if (lr == 0){
        int co = wm*64 + m*16 + lh*4 + j;
        atomicAdd(&part[((size_t)(n&15)*COUT + co)*2],   s);
        atomicAdd(&part[((size_t)(n&15)*COUT + co)*2+1], qq);
      }
    }
  }
}

// ---------------- BN2: inline fin + apply + ReLU; reads h2b bf16, writes out f32 ----------------
__global__ void k_bn2(float* __restrict__ out, const int* __restrict__ bidx,
                      const unsigned short* __restrict__ h2b,
                      const float* __restrict__ part, const float* __restrict__ g,
                      const float* __restrict__ be, float inv){
  __shared__ float sst[512];
  int cq = blockIdx.x, n = blockIdx.y, t = threadIdx.x;
  {
    float s = 0.f, q = 0.f;
    #pragma unroll
    for (int gi = 0; gi < 16; ++gi){
      const float* p = part + ((size_t)gi*COUT + t)*2;
      s += p[0]; q += p[1];
    }
    float mu = s*inv, var = q*inv - mu*mu;
    float sc = g[t]*rsqrtf(var + 1e-5f);
    sst[t] = sc; sst[256+t] = be[t] - mu*sc;
  }
  __syncthreads();
  int bi = bidx[n*3], by = bidx[n*3+1], bx = bidx[n*3+2];
  int px0 = t*4; int ly = px0>>5, lx = px0&31;
  const unsigned short* h2n = h2b + ((size_t)n << 18);
  float* base = out + (size_t)bi*COUT*HH*WW + (size_t)(by*BSZ+ly)*WW + bx*BSZ + lx;
  for (int c = 0; c < 64; ++c){
    int co = cq*64 + c;
    float sc = sst[co], tc = sst[256+co];
    ushort4 hv = *(const ushort4*)&h2n[(((size_t)co)<<10) + px0];
    float4 v;
    v.x = fmaxf(bf2f(hv.x)*sc+tc, 0.f); v.y = fmaxf(bf2f(hv.y)*sc+tc, 0.f);
    v.z = fmaxf(bf2f(hv.z)*sc+tc, 0.f); v.w = fmaxf(bf2f(hv.w)*sc+tc, 0.f);
    *(float4*)(base + (size_t)co*HH*WW) = v;
  }
}

extern "C" void kernel_launch(void* const* d_in, const int* in_sizes, int n_in,
                              void* d_out, int out_size, void* d_ws, size_t ws_size,
                              hipStream_t stream){
  const float* x   = (const float*)d_in[0];
  const float* w1  = (const float*)d_in[1];
  const float* g1  = (const float*)d_in[3];
  const float* be1 = (const float*)d_in[4];
  const float* w2  = (const float*)d_in[5];
  const float* g2  = (const float*)d_in[7];
  const float* be2 = (const float*)d_in[8];
  const float* wd  = (const float*)d_in[9];
  const float* bd  = (const float*)d_in[10];
  const int* bidx  = (const int*)d_in[11];
  float* out = (float*)d_out;
  const int nact = in_sizes[11]/3;     // 128

  char* wsp = (char*)d_ws;
  size_t off = 0;
  auto carve = [&](size_t bytes)->char*{
    char* p = wsp + off; off += (bytes + 255) & ~(size_t)255; return p;
  };
  unsigned short* h1p = (unsigned short*)carve((size_t)nact*PIX2*COUT*2 + 4096);
  unsigned short* h2b = (unsigned short*)carve((size_t)nact*1024*COUT*2);
  unsigned short* w1b = (unsigned short*)carve((size_t)COUT*CIN*2);
  unsigned short* wdb = (unsigned short*)carve((size_t)COUT*CIN*2);
  unsigned short* w2t = (unsigned short*)carve((size_t)9*COUT*COUT*2);
  float* part1 = (float*)carve((size_t)16*COUT*2*4);
  float* part2 = (float*)carve((size_t)16*COUT*2*4);
  int* inact   = (int*)carve(NBLK*4);

  const float inv = 1.0f/((float)nact*1024.0f);
  k_prep<<<2313, 256, 0, stream>>>(w1, wd, w2, w1b, wdb, w2t,
                                   bidx, nact, inact, part1, part2);
  k_gemm1<<<dim3(8, 2, NBLK), 256, 0, stream>>>(x, w1b, wdb, bidx, inact, bd,
                                                h1p, out, part1, nact);
  k_bn1<<<dim3(nact*32), 256, 0, stream>>>(h1p, part1, g1, be1, inv);
  k_conv2<<<dim3(8, nact), 512, 0, stream>>>(h1p, w2t, bidx, h2b, part2);
  k_bn2<<<dim3(4, nact), 256, 0, stream>>>(out, bidx, h2b, part2, g2, be2, inv);
}